// Round 3
// baseline (748.243 us; speedup 1.0000x reference)
//
#include <hip/hip_runtime.h>
#include <hip/hip_bf16.h>
#include <hip/hip_fp16.h>

// KAN layer as one fp16 MFMA GEMM with 9x expanded K (k = i*9 + c).
// R3: XCD-aware swizzle (W L2-resident per XCD), S=2 split-K, coalesced preps.
#define BATCH 4096
#define IN_F  2048
#define OUT_F 2048
#define KDIM  (IN_F * 9)   // 18432
#define MN    ((size_t)BATCH * OUT_F)

typedef __attribute__((ext_vector_type(8))) _Float16 f16x8;
typedef __attribute__((ext_vector_type(4))) float    f32x4;

// ---------------- prep: merged weights, fp16, K-major [o][i*9+c] ----------------
// Coalesced float4 reads -> fp16 scatter into LDS image -> coalesced 16B stores.
__global__ __launch_bounds__(256) void prep_W(const float* __restrict__ bw,
                                              const float* __restrict__ sw,
                                              _Float16* __restrict__ W) {
  __shared__ _Float16 buf[2048 * 9];          // 36 KB, final interleaved layout
  const int t = threadIdx.x;
  const size_t eb = (size_t)blockIdx.x * 2048;   // first flat (o,i) element

  const float4* bv = (const float4*)(bw + eb);   // 512 float4
#pragma unroll
  for (int p = 0; p < 2; ++p) {
    int idx = p * 256 + t;                       // coalesced
    float4 v = bv[idx];
    buf[(idx * 4 + 0) * 9] = (_Float16)v.x;
    buf[(idx * 4 + 1) * 9] = (_Float16)v.y;
    buf[(idx * 4 + 2) * 9] = (_Float16)v.z;
    buf[(idx * 4 + 3) * 9] = (_Float16)v.w;
  }
  const float4* sv = (const float4*)(sw + eb * 8);  // 4096 float4
#pragma unroll
  for (int p = 0; p < 16; ++p) {
    int idx = p * 256 + t;                       // coalesced
    float4 v = sv[idx];
    int e = idx >> 1, g0 = (idx & 1) * 4;
    _Float16* d = buf + e * 9 + 1 + g0;
    d[0] = (_Float16)(0.1f * v.x);
    d[1] = (_Float16)(0.1f * v.y);
    d[2] = (_Float16)(0.1f * v.z);
    d[3] = (_Float16)(0.1f * v.w);
  }
  __syncthreads();
  const f16x8* src = (const f16x8*)buf;
  f16x8* dst = (f16x8*)(W + eb * 9);
#pragma unroll
  for (int c = 0; c < 9; ++c)
    dst[c * 256 + t] = src[c * 256 + t];         // coalesced 16B stores
}

// ---------------- prep: features, fp16, K-major [b][i*9+c] ----------------
__global__ __launch_bounds__(256) void prep_A(const float* __restrict__ x,
                                              const float* __restrict__ kn,
                                              _Float16* __restrict__ A) {
  __shared__ _Float16 buf[2048 * 9];
  const int t = threadIdx.x;
  const size_t eb = (size_t)blockIdx.x * 2048;
  float k[8];
#pragma unroll
  for (int g = 0; g < 8; ++g) k[g] = kn[g];

  const float4* xv = (const float4*)(x + eb);    // 512 float4
#pragma unroll
  for (int p = 0; p < 2; ++p) {
    int idx = p * 256 + t;                       // coalesced
    float4 v4 = xv[idx];
    float vv[4] = {v4.x, v4.y, v4.z, v4.w};
#pragma unroll
    for (int q = 0; q < 4; ++q) {
      _Float16* d = buf + (idx * 4 + q) * 9;
      d[0] = (_Float16)vv[q];
#pragma unroll
      for (int g = 0; g < 8; ++g) {
        float r = vv[q] - k[g];
        d[1 + g] = (_Float16)(r > 0.f ? r : 0.f);
      }
    }
  }
  __syncthreads();
  const f16x8* src = (const f16x8*)buf;
  f16x8* dst = (f16x8*)(A + eb * 9);
#pragma unroll
  for (int c = 0; c < 9; ++c)
    dst[c * 256 + t] = src[c * 256 + t];
}

// ---------------- GEMM: C[M,N] = A[M,K] @ W[N,K]^T, fp16 in / fp32 out ----------------
// XOR-swizzled LDS (conflict-free ds_read_b128). 1-D grid with XCD-aware
// decode: xcd = bid&7 owns N-cols [xcd*256, xcd*256+256); within an XCD the
// M-sweep (y fastest) keeps a 2.36 MB W chunk L2-resident.
#define BM 128
#define BN 128
#define BK 64

template <int S>
__global__ __launch_bounds__(256) void gemm_bt(const _Float16* __restrict__ A,
                                               const _Float16* __restrict__ W,
                                               float* __restrict__ C,
                                               size_t zstride) {
  constexpr int K = KDIM, N = OUT_F, KC = KDIM / S;
  __shared__ _Float16 As[BM * BK];   // 16 KB
  __shared__ _Float16 Bs[BN * BK];   // 16 KB

  const int tid  = threadIdx.x;
  const int lane = tid & 63;
  const int wv   = tid >> 6;
  const int wm   = wv >> 1;
  const int wn   = wv & 1;

  // XCD-aware decode of 1-D block id (16/S per-XCD x-tiles x 32 y x S z)
  const int bid = blockIdx.x;
  const int xcd = bid & 7;
  const int r   = bid >> 3;
  const int y   = r & 31;
  const int z   = (S > 1) ? ((r >> 5) & (S - 1)) : 0;
  const int x2  = (S > 1) ? (r >> (5 + (S == 2 ? 1 : 2))) : (r >> 5);
  const int m0  = y * BM;
  const int n0  = (xcd * 2 + x2) * BN;
  const int kBeg = z * KC;
  const int kEnd = kBeg + KC;
  float* Cd = C + (size_t)z * zstride;

  f32x4 acc[4][4] = {};

  // staging: 256 thr x 16B = 32 rows/pass, 4 passes. LDS dest = base + tid*16.
  const int rowS = tid >> 3;                           // 0..31
  const int kgS  = ((tid & 7) ^ (rowS & 7)) * 8;       // swizzled global chunk

  for (int k0 = kBeg; k0 < kEnd; k0 += BK) {
#pragma unroll
    for (int p = 0; p < 4; ++p) {
      const int r2 = p * 32 + rowS;
      const _Float16* ga = A + (size_t)(m0 + r2) * K + k0 + kgS;
      const _Float16* gw = W + (size_t)(n0 + r2) * K + k0 + kgS;
      __builtin_amdgcn_global_load_lds(
          (const __attribute__((address_space(1))) void*)ga,
          (__attribute__((address_space(3))) void*)(As + r2 * BK + (tid & 7) * 8), 16, 0, 0);
      __builtin_amdgcn_global_load_lds(
          (const __attribute__((address_space(1))) void*)gw,
          (__attribute__((address_space(3))) void*)(Bs + r2 * BK + (tid & 7) * 8), 16, 0, 0);
    }
    __syncthreads();

#pragma unroll
    for (int kk = 0; kk < BK; kk += 32) {
      const int koff = (((kk >> 3) + (lane >> 4)) ^ (lane & 7)) * 8;
      f16x8 af[4], bfr[4];
#pragma unroll
      for (int mi = 0; mi < 4; ++mi) {
        const int rr = wm * 64 + mi * 16 + (lane & 15);
        af[mi] = *(const f16x8*)(As + rr * BK + koff);   // conflict-free b128
      }
#pragma unroll
      for (int ni = 0; ni < 4; ++ni) {
        const int rr = wn * 64 + ni * 16 + (lane & 15);
        bfr[ni] = *(const f16x8*)(Bs + rr * BK + koff);
      }
#pragma unroll
      for (int mi = 0; mi < 4; ++mi)
#pragma unroll
        for (int ni = 0; ni < 4; ++ni)
          acc[mi][ni] = __builtin_amdgcn_mfma_f32_16x16x32_f16(af[mi], bfr[ni],
                                                               acc[mi][ni], 0, 0, 0);
    }
    __syncthreads();
  }

  // C/D layout: col=lane&15, row=(lane>>4)*4+reg
  const int cn = lane & 15;
  const int r4 = (lane >> 4) * 4;
#pragma unroll
  for (int mi = 0; mi < 4; ++mi) {
    const int rowb = m0 + wm * 64 + mi * 16 + r4;
#pragma unroll
    for (int ni = 0; ni < 4; ++ni) {
      const int col = n0 + wn * 64 + ni * 16 + cn;
#pragma unroll
      for (int reg = 0; reg < 4; ++reg)
        Cd[(size_t)(rowb + reg) * N + col] = acc[mi][ni][reg];
    }
  }
}

// ---------------- split-K reduce ----------------
template <int S>
__global__ __launch_bounds__(256) void reduceK(const float* __restrict__ part,
                                               float* __restrict__ out) {
  const size_t i = ((size_t)blockIdx.x * 256 + threadIdx.x) * 4;
  f32x4 a = *(const f32x4*)(part + i);
#pragma unroll
  for (int s = 1; s < S; ++s)
    a += *(const f32x4*)(part + (size_t)s * MN + i);
  *(f32x4*)(out + i) = a;
}

// ---------------- fallback: fp32, wave per (b,o) ----------------
__global__ __launch_bounds__(256) void kan_naive(const float* __restrict__ x,
                                                 const float* __restrict__ bw,
                                                 const float* __restrict__ sw,
                                                 const float* __restrict__ kn,
                                                 float* __restrict__ out) {
  const int lane = threadIdx.x & 63;
  const int o = blockIdx.x * 4 + (threadIdx.x >> 6);
  const int b = blockIdx.y;
  float k[8];
#pragma unroll
  for (int g = 0; g < 8; ++g) k[g] = kn[g];
  float acc = 0.f;
  for (int i = lane; i < IN_F; i += 64) {
    const float v = x[(size_t)b * IN_F + i];
    float sp = 0.f;
    const float* s = sw + ((size_t)o * IN_F + i) * 8;
#pragma unroll
    for (int g = 0; g < 8; ++g) {
      float r = v - k[g];
      sp += s[g] * (r > 0.f ? r : 0.f);
    }
    acc += v * bw[(size_t)o * IN_F + i] + 0.1f * sp;
  }
#pragma unroll
  for (int off = 32; off; off >>= 1) acc += __shfl_down(acc, off, 64);
  if (lane == 0) out[(size_t)b * OUT_F + o] = acc;
}

extern "C" void kernel_launch(void* const* d_in, const int* in_sizes, int n_in,
                              void* d_out, int out_size, void* d_ws, size_t ws_size,
                              hipStream_t stream) {
  const float* x  = (const float*)d_in[0];
  const float* bw = (const float*)d_in[1];
  const float* sw = (const float*)d_in[2];
  const float* kn = (const float*)d_in[3];
  float* out = (float*)d_out;

  const size_t wbytes = (size_t)OUT_F * KDIM * sizeof(_Float16);   // 72 MB
  const size_t abytes = (size_t)BATCH * KDIM * sizeof(_Float16);   // 144 MB
  const size_t pbytes = MN * sizeof(float);                        // 32 MB per split

  if (ws_size < wbytes + abytes) {
    dim3 grid(OUT_F / 4, BATCH);
    kan_naive<<<grid, 256, 0, stream>>>(x, bw, sw, kn, out);
    return;
  }

  _Float16* W = (_Float16*)d_ws;
  _Float16* A = (_Float16*)((char*)d_ws + wbytes);
  float* part  = (float*)((char*)d_ws + wbytes + abytes);

  prep_W<<<(OUT_F * IN_F) / 2048, 256, 0, stream>>>(bw, sw, W);
  prep_A<<<(BATCH * IN_F) / 2048, 256, 0, stream>>>(x, kn, A);

  if (ws_size >= wbytes + abytes + 2 * pbytes) {
    gemm_bt<2><<<1024, 256, 0, stream>>>(A, W, part, MN);
    reduceK<2><<<MN / 1024, 256, 0, stream>>>(part, out);
  } else {
    gemm_bt<1><<<512, 256, 0, stream>>>(A, W, out, 0);
  }
}

// Round 4
// 522.712 us; speedup vs baseline: 1.4315x; 1.4315x over previous
//
#include <hip/hip_runtime.h>
#include <hip/hip_bf16.h>
#include <hip/hip_fp16.h>

// KAN layer = fp16 MFMA GEMM over g-major expanded K: k = p*2048 + i,
// plane p=0: feature x, weight bw; planes p=1..8: feature relu(x-kn[p-1]),
// weight 0.1*sw[o,i,p-1].
// R4: NO A image — stage the x-tile once per i-block and derive all 9 plane
// fragments in-register (relu is scalar-shift+clamp, hidden under MFMA).
// Unique GEMM footprint 89 MB (LLC-resident); W chunk L2-resident per XCD.
#define BATCH 4096
#define IN_F  2048
#define OUT_F 2048
#define NPLANE 9
#define KDIM  (IN_F * NPLANE)        // 18432
#define MN    ((size_t)BATCH * OUT_F)

typedef __attribute__((ext_vector_type(8))) _Float16 f16x8;
typedef __attribute__((ext_vector_type(2))) _Float16 f16x2;
typedef __attribute__((ext_vector_type(4))) float    f32x4;

// ---------------- prep: x fp32 -> fp16 image [b][i] ----------------
__global__ __launch_bounds__(256) void prep_X(const float* __restrict__ x,
                                              _Float16* __restrict__ X) {
  const size_t idx = ((size_t)blockIdx.x * 256 + threadIdx.x) * 8;
  const float4* v = (const float4*)(x + idx);
  float4 a = v[0], b = v[1];
  f16x8 o;
  o[0]=(_Float16)a.x; o[1]=(_Float16)a.y; o[2]=(_Float16)a.z; o[3]=(_Float16)a.w;
  o[4]=(_Float16)b.x; o[5]=(_Float16)b.y; o[6]=(_Float16)b.z; o[7]=(_Float16)b.w;
  *(f16x8*)(X + idx) = o;
}

// ---------------- prep: base weight -> plane 0 of W [o][p*2048+i] ----------------
__global__ __launch_bounds__(256) void prep_Wb(const float* __restrict__ bw,
                                               _Float16* __restrict__ W) {
  const size_t idx = ((size_t)blockIdx.x * 256 + threadIdx.x) * 8;
  const int o = (int)(idx >> 11), i = (int)(idx & 2047);
  const float4* v = (const float4*)(bw + idx);
  float4 a = v[0], b = v[1];
  f16x8 h;
  h[0]=(_Float16)a.x; h[1]=(_Float16)a.y; h[2]=(_Float16)a.z; h[3]=(_Float16)a.w;
  h[4]=(_Float16)b.x; h[5]=(_Float16)b.y; h[6]=(_Float16)b.z; h[7]=(_Float16)b.w;
  *(f16x8*)(W + (size_t)o * KDIM + i) = h;
}

// ---------------- prep: spline weights -> planes 1..8 of W ----------------
// thread handles 2 consecutive (o,i) elements: 4 coalesced float4 reads,
// 8 half2 stores (one per plane, lane-contiguous).
__global__ __launch_bounds__(256) void prep_Ws(const float* __restrict__ sw,
                                               _Float16* __restrict__ W) {
  const size_t e = ((size_t)blockIdx.x * 256 + threadIdx.x) * 2;   // even
  const int o = (int)(e >> 11), i = (int)(e & 2047);
  const float4* s = (const float4*)(sw + e * 8);
  float4 q0 = s[0], q1 = s[1], q2 = s[2], q3 = s[3];
  float g0[8] = {q0.x,q0.y,q0.z,q0.w,q1.x,q1.y,q1.z,q1.w};
  float g1[8] = {q2.x,q2.y,q2.z,q2.w,q3.x,q3.y,q3.z,q3.w};
  _Float16* base = W + (size_t)o * KDIM + i;
#pragma unroll
  for (int p = 1; p <= 8; ++p) {
    f16x2 h;
    h[0] = (_Float16)(0.1f * g0[p-1]);
    h[1] = (_Float16)(0.1f * g1[p-1]);
    *(f16x2*)(base + p * IN_F) = h;
  }
}

// ---------------- GEMM ----------------
#define BM 128
#define BN 128
#define BK 64

__device__ inline f16x8 relu_shift(f16x8 x, _Float16 kg) {
  f16x8 r;
#pragma unroll
  for (int j = 0; j < 8; ++j) {
    _Float16 d = x[j] - kg;
    r[j] = d > (_Float16)0 ? d : (_Float16)0;
  }
  return r;
}

template <int S>
__global__ __launch_bounds__(256) void gemm_kan(const _Float16* __restrict__ X,
                                                const _Float16* __restrict__ W,
                                                const float* __restrict__ kn,
                                                float* __restrict__ C,
                                                size_t zstride) {
  constexpr int N = OUT_F;
  __shared__ _Float16 Xs[BM * BK];   // 16 KB, x-tile (per i-block, reused 9x)
  __shared__ _Float16 Ws[BN * BK];   // 16 KB, current W plane tile

  const int tid  = threadIdx.x;
  const int lane = tid & 63;
  const int wv   = tid >> 6;
  const int wm   = wv >> 1;
  const int wn   = wv & 1;

  // XCD-aware 1-D decode: xcd owns 2 n-tiles; y (M) sweeps fastest.
  const int bid = blockIdx.x;
  const int xcd = bid & 7;
  const int r   = bid >> 3;
  const int y   = r & 31;
  const int z   = (S > 1) ? ((r >> 5) & (S - 1)) : 0;
  const int x2  = (S > 1) ? (r >> 6) : (r >> 5);
  const int m0  = y * BM;
  const int n0  = (xcd * 2 + x2) * BN;
  float* Cd = C + (size_t)z * zstride;

  _Float16 kh[8];
#pragma unroll
  for (int j = 0; j < 8; ++j) kh[j] = (_Float16)kn[j];

  f32x4 acc[4][4] = {};

  // staging: 256 thr x 16B = 32 rows/pass, 4 passes. XOR swizzle on the
  // GLOBAL chunk (LDS dest must stay base + tid*16 for global_load_lds).
  const int rowS = tid >> 3;                        // 0..31
  const int kgS  = ((tid & 7) ^ (rowS & 7)) * 8;    // swizzled source chunk
  const int ldst = (tid & 7) * 8;                   // LDS chunk

  const int ibBeg = z * (32 / S), ibEnd = ibBeg + 32 / S;
  for (int ib = ibBeg; ib < ibEnd; ++ib) {
    const int i0 = ib * BK;

    // ---- plane 0: stage X-tile + W plane-0 tile ----
#pragma unroll
    for (int p4 = 0; p4 < 4; ++p4) {
      const int r2 = p4 * 32 + rowS;
      __builtin_amdgcn_global_load_lds(
          (const __attribute__((address_space(1))) void*)(X + (size_t)(m0 + r2) * IN_F + i0 + kgS),
          (__attribute__((address_space(3))) void*)(Xs + r2 * BK + ldst), 16, 0, 0);
      __builtin_amdgcn_global_load_lds(
          (const __attribute__((address_space(1))) void*)(W + (size_t)(n0 + r2) * KDIM + i0 + kgS),
          (__attribute__((address_space(3))) void*)(Ws + r2 * BK + ldst), 16, 0, 0);
    }
    __syncthreads();

    // X fragments: read once, reuse for all 9 planes (held in VGPRs)
    f16x8 xf[4][2];
#pragma unroll
    for (int s = 0; s < 2; ++s) {
      const int koff = (((s * 4) + (lane >> 4)) ^ (lane & 7)) * 8;
#pragma unroll
      for (int mi = 0; mi < 4; ++mi)
        xf[mi][s] = *(const f16x8*)(Xs + (wm * 64 + mi * 16 + (lane & 15)) * BK + koff);
    }

    // plane 0 compute: feature = x
#pragma unroll
    for (int s = 0; s < 2; ++s) {
      const int koff = (((s * 4) + (lane >> 4)) ^ (lane & 7)) * 8;
      f16x8 bfr[4];
#pragma unroll
      for (int ni = 0; ni < 4; ++ni)
        bfr[ni] = *(const f16x8*)(Ws + (wn * 64 + ni * 16 + (lane & 15)) * BK + koff);
#pragma unroll
      for (int mi = 0; mi < 4; ++mi)
#pragma unroll
        for (int ni = 0; ni < 4; ++ni)
          acc[mi][ni] = __builtin_amdgcn_mfma_f32_16x16x32_f16(xf[mi][s], bfr[ni],
                                                               acc[mi][ni], 0, 0, 0);
    }
    __syncthreads();

    // ---- planes 1..8: stage W plane tile, feature = relu(x - kn[p-1]) ----
#pragma unroll
    for (int p = 1; p < NPLANE; ++p) {
#pragma unroll
      for (int p4 = 0; p4 < 4; ++p4) {
        const int r2 = p4 * 32 + rowS;
        __builtin_amdgcn_global_load_lds(
            (const __attribute__((address_space(1))) void*)(W + (size_t)(n0 + r2) * KDIM + p * IN_F + i0 + kgS),
            (__attribute__((address_space(3))) void*)(Ws + r2 * BK + ldst), 16, 0, 0);
      }
      __syncthreads();
      const _Float16 kg = kh[p - 1];
#pragma unroll
      for (int s = 0; s < 2; ++s) {
        const int koff = (((s * 4) + (lane >> 4)) ^ (lane & 7)) * 8;
        f16x8 bfr[4];
#pragma unroll
        for (int ni = 0; ni < 4; ++ni)
          bfr[ni] = *(const f16x8*)(Ws + (wn * 64 + ni * 16 + (lane & 15)) * BK + koff);
#pragma unroll
        for (int mi = 0; mi < 4; ++mi) {
          const f16x8 af = relu_shift(xf[mi][s], kg);
#pragma unroll
          for (int ni = 0; ni < 4; ++ni)
            acc[mi][ni] = __builtin_amdgcn_mfma_f32_16x16x32_f16(af, bfr[ni],
                                                                 acc[mi][ni], 0, 0, 0);
        }
      }
      __syncthreads();
    }
  }

  // epilogue: C/D layout col=lane&15, row=(lane>>4)*4+reg
  const int cn = lane & 15;
  const int r4 = (lane >> 4) * 4;
#pragma unroll
  for (int mi = 0; mi < 4; ++mi) {
    const int rowb = m0 + wm * 64 + mi * 16 + r4;
#pragma unroll
    for (int ni = 0; ni < 4; ++ni) {
      const int col = n0 + wn * 64 + ni * 16 + cn;
#pragma unroll
      for (int reg = 0; reg < 4; ++reg)
        Cd[(size_t)(rowb + reg) * N + col] = acc[mi][ni][reg];
    }
  }
}

// ---------------- split-K reduce ----------------
template <int S>
__global__ __launch_bounds__(256) void reduceK(const float* __restrict__ part,
                                               float* __restrict__ out) {
  const size_t i = ((size_t)blockIdx.x * 256 + threadIdx.x) * 4;
  f32x4 a = *(const f32x4*)(part + i);
#pragma unroll
  for (int s = 1; s < S; ++s)
    a += *(const f32x4*)(part + (size_t)s * MN + i);
  *(f32x4*)(out + i) = a;
}

// ---------------- fallback: fp32, wave per (b,o) ----------------
__global__ __launch_bounds__(256) void kan_naive(const float* __restrict__ x,
                                                 const float* __restrict__ bw,
                                                 const float* __restrict__ sw,
                                                 const float* __restrict__ kn,
                                                 float* __restrict__ out) {
  const int lane = threadIdx.x & 63;
  const int o = blockIdx.x * 4 + (threadIdx.x >> 6);
  const int b = blockIdx.y;
  float k[8];
#pragma unroll
  for (int g = 0; g < 8; ++g) k[g] = kn[g];
  float acc = 0.f;
  for (int i = lane; i < IN_F; i += 64) {
    const float v = x[(size_t)b * IN_F + i];
    float sp = 0.f;
    const float* s = sw + ((size_t)o * IN_F + i) * 8;
#pragma unroll
    for (int g = 0; g < 8; ++g) {
      float r = v - k[g];
      sp += s[g] * (r > 0.f ? r : 0.f);
    }
    acc += v * bw[(size_t)o * IN_F + i] + 0.1f * sp;
  }
#pragma unroll
  for (int off = 32; off; off >>= 1) acc += __shfl_down(acc, off, 64);
  if (lane == 0) out[(size_t)b * OUT_F + o] = acc;
}

extern "C" void kernel_launch(void* const* d_in, const int* in_sizes, int n_in,
                              void* d_out, int out_size, void* d_ws, size_t ws_size,
                              hipStream_t stream) {
  const float* x  = (const float*)d_in[0];
  const float* bw = (const float*)d_in[1];
  const float* sw = (const float*)d_in[2];
  const float* kn = (const float*)d_in[3];
  float* out = (float*)d_out;

  const size_t wbytes = (size_t)OUT_F * KDIM * sizeof(_Float16);   // 75.5 MB
  const size_t xbytes = (size_t)BATCH * IN_F * sizeof(_Float16);   // 16.8 MB
  const size_t pbytes = MN * sizeof(float);                        // 33.5 MB

  if (ws_size < wbytes + xbytes) {
    dim3 grid(OUT_F / 4, BATCH);
    kan_naive<<<grid, 256, 0, stream>>>(x, bw, sw, kn, out);
    return;
  }

  _Float16* W  = (_Float16*)d_ws;
  _Float16* X  = (_Float16*)((char*)d_ws + wbytes);
  float*    part = (float*)((char*)d_ws + wbytes + xbytes);

  prep_X <<<(BATCH * IN_F) / 8 / 256, 256, 0, stream>>>(x, X);
  prep_Wb<<<(OUT_F * IN_F) / 8 / 256, 256, 0, stream>>>(bw, W);
  prep_Ws<<<(OUT_F * IN_F) / 2 / 256, 256, 0, stream>>>(sw, W);

  if (ws_size >= wbytes + xbytes + 2 * pbytes) {
    gemm_kan<2><<<1024, 256, 0, stream>>>(X, W, kn, part, MN);
    reduceK<2><<<MN / 1024, 256, 0, stream>>>(part, out);
  } else {
    gemm_kan<1><<<512, 256, 0, stream>>>(X, W, kn, out, 0);
  }
}

// Round 5
// 509.386 us; speedup vs baseline: 1.4689x; 1.0262x over previous
//
#include <hip/hip_runtime.h>
#include <hip/hip_bf16.h>
#include <hip/hip_fp16.h>

// KAN layer = fp16 MFMA GEMM over g-major expanded K: k = p*2048 + i.
// plane p=0: feature x, weight bw; planes p=1..8: feature relu(x-kn[p-1]),
// weight 0.1*sw[o,i,p-1]. Features derived in-register from a per-i-block
// x-tile (no A image).
// R5: double-buffered W-plane tiles with prefetch-after-barrier (1 barrier
// per plane, drain covered by compute), S=1 direct-write (no reduce), fused
// weight prep.
#define BATCH 4096
#define IN_F  2048
#define OUT_F 2048
#define NPLANE 9
#define KDIM  (IN_F * NPLANE)        // 18432
#define MN    ((size_t)BATCH * OUT_F)

typedef __attribute__((ext_vector_type(8))) _Float16 f16x8;
typedef __attribute__((ext_vector_type(2))) _Float16 f16x2;
typedef __attribute__((ext_vector_type(4))) float    f32x4;

// ---------------- prep: x fp32 -> fp16 image [b][i] ----------------
__global__ __launch_bounds__(256) void prep_X(const float* __restrict__ x,
                                              _Float16* __restrict__ X) {
  const size_t idx = ((size_t)blockIdx.x * 256 + threadIdx.x) * 8;
  const float4* v = (const float4*)(x + idx);
  float4 a = v[0], b = v[1];
  f16x8 o;
  o[0]=(_Float16)a.x; o[1]=(_Float16)a.y; o[2]=(_Float16)a.z; o[3]=(_Float16)a.w;
  o[4]=(_Float16)b.x; o[5]=(_Float16)b.y; o[6]=(_Float16)b.z; o[7]=(_Float16)b.w;
  *(f16x8*)(X + idx) = o;
}

// ---------------- prep: bw + sw -> W image [o][p*2048+i], all 9 planes ----------------
// thread handles 2 consecutive (o,i) elements: 8B bw read, 4 float4 sw reads,
// 9 f16x2 stores (lane-contiguous 256B segments per wave).
__global__ __launch_bounds__(256) void prep_W(const float* __restrict__ bw,
                                              const float* __restrict__ sw,
                                              _Float16* __restrict__ W) {
  const size_t e = ((size_t)blockIdx.x * 256 + threadIdx.x) * 2;   // even
  const int o = (int)(e >> 11), i = (int)(e & 2047);
  _Float16* base = W + (size_t)o * KDIM + i;

  const float2* b2 = (const float2*)(bw + e);
  float2 bb = b2[0];
  f16x2 h0; h0[0] = (_Float16)bb.x; h0[1] = (_Float16)bb.y;
  *(f16x2*)base = h0;

  const float4* s = (const float4*)(sw + e * 8);
  float4 q0 = s[0], q1 = s[1], q2 = s[2], q3 = s[3];
  float g0[8] = {q0.x,q0.y,q0.z,q0.w,q1.x,q1.y,q1.z,q1.w};
  float g1[8] = {q2.x,q2.y,q2.z,q2.w,q3.x,q3.y,q3.z,q3.w};
#pragma unroll
  for (int p = 1; p <= 8; ++p) {
    f16x2 h;
    h[0] = (_Float16)(0.1f * g0[p-1]);
    h[1] = (_Float16)(0.1f * g1[p-1]);
    *(f16x2*)(base + p * IN_F) = h;
  }
}

// ---------------- GEMM ----------------
#define BM 128
#define BN 128
#define BK 64

__device__ inline f16x8 relu_shift(f16x8 x, _Float16 kg) {
  f16x8 r;
#pragma unroll
  for (int j = 0; j < 8; ++j) {
    _Float16 d = x[j] - kg;
    r[j] = d > (_Float16)0 ? d : (_Float16)0;
  }
  return r;
}

__global__ __launch_bounds__(256) void gemm_kan(const _Float16* __restrict__ X,
                                                const _Float16* __restrict__ W,
                                                const float* __restrict__ kn,
                                                float* __restrict__ C) {
  constexpr int N = OUT_F;
  __shared__ _Float16 Xs[BM * BK];        // 16 KB, x-tile (dead after frag read)
  __shared__ _Float16 Ws[2][BN * BK];     // 2 x 16 KB, double-buffered W plane

  const int tid  = threadIdx.x;
  const int lane = tid & 63;
  const int wv   = tid >> 6;
  const int wm   = wv >> 1;
  const int wn   = wv & 1;

  // XCD-aware decode: xcd = bid&7 owns 2 n-tiles (2.36 MB W, L2-resident);
  // y (M) sweeps fastest within an XCD.
  const int bid = blockIdx.x;
  const int xcd = bid & 7;
  const int r   = bid >> 3;
  const int y   = r & 31;
  const int x2  = r >> 5;
  const int m0  = y * BM;
  const int n0  = (xcd * 2 + x2) * BN;

  _Float16 kh[8];
#pragma unroll
  for (int j = 0; j < 8; ++j) kh[j] = (_Float16)kn[j];

  f32x4 acc[4][4] = {};

  // staging: 256 thr x 16B = 32 rows/pass, 4 passes. XOR swizzle applied to
  // the GLOBAL chunk (LDS dest must stay base + tid*16 for global_load_lds).
  const int rowS = tid >> 3;                        // 0..31
  const int kgS  = ((tid & 7) ^ (rowS & 7)) * 8;    // swizzled source chunk
  const int ldst = (tid & 7) * 8;                   // LDS chunk

  const _Float16* Wrow = W + kgS;   // + (n0+r2)*KDIM + p*IN_F + i0
  const _Float16* Xrow = X + kgS;   // + (m0+r2)*IN_F + i0

  // prologue: stage X(0) and W(plane0, ib0) into Ws[0]
#pragma unroll
  for (int p4 = 0; p4 < 4; ++p4) {
    const int r2 = p4 * 32 + rowS;
    __builtin_amdgcn_global_load_lds(
        (const __attribute__((address_space(1))) void*)(Xrow + (size_t)(m0 + r2) * IN_F),
        (__attribute__((address_space(3))) void*)(Xs + r2 * BK + ldst), 16, 0, 0);
    __builtin_amdgcn_global_load_lds(
        (const __attribute__((address_space(1))) void*)(Wrow + (size_t)(n0 + r2) * KDIM),
        (__attribute__((address_space(3))) void*)(Ws[0] + r2 * BK + ldst), 16, 0, 0);
  }
  __syncthreads();

  int cur = 0;
  for (int ib = 0; ib < 32; ++ib) {
    const int i0 = ib * BK;

    // X fragments for this i-block (Xs is dead afterwards)
    f16x8 xf[4][2];
#pragma unroll
    for (int s = 0; s < 2; ++s) {
      const int koff = (((s * 4) + (lane >> 4)) ^ (lane & 7)) * 8;
#pragma unroll
      for (int mi = 0; mi < 4; ++mi)
        xf[mi][s] = *(const f16x8*)(Xs + (wm * 64 + mi * 16 + (lane & 15)) * BK + koff);
    }

#pragma unroll
    for (int p = 0; p < NPLANE; ++p) {
      // ---- prefetch next stage into the other buffer (no wait) ----
      const int nxt = cur ^ 1;
      if (p < NPLANE - 1) {
        const int off = (p + 1) * IN_F + i0;
#pragma unroll
        for (int p4 = 0; p4 < 4; ++p4) {
          const int r2 = p4 * 32 + rowS;
          __builtin_amdgcn_global_load_lds(
              (const __attribute__((address_space(1))) void*)(Wrow + (size_t)(n0 + r2) * KDIM + off),
              (__attribute__((address_space(3))) void*)(Ws[nxt] + r2 * BK + ldst), 16, 0, 0);
        }
      } else if (ib < 31) {
        const int off = i0 + BK;   // next i-block, plane 0
#pragma unroll
        for (int p4 = 0; p4 < 4; ++p4) {
          const int r2 = p4 * 32 + rowS;
          __builtin_amdgcn_global_load_lds(
              (const __attribute__((address_space(1))) void*)(Wrow + (size_t)(n0 + r2) * KDIM + off),
              (__attribute__((address_space(3))) void*)(Ws[nxt] + r2 * BK + ldst), 16, 0, 0);
        }
      }
      if (p == 1 && ib < 31) {   // Xs reads done by all threads (plane-0 sync passed)
        const int off = i0 + BK;
#pragma unroll
        for (int p4 = 0; p4 < 4; ++p4) {
          const int r2 = p4 * 32 + rowS;
          __builtin_amdgcn_global_load_lds(
              (const __attribute__((address_space(1))) void*)(Xrow + (size_t)(m0 + r2) * IN_F + off),
              (__attribute__((address_space(3))) void*)(Xs + r2 * BK + ldst), 16, 0, 0);
        }
      }

      // ---- compute plane p from Ws[cur] ----
      const _Float16* Wc = Ws[cur];
#pragma unroll
      for (int s = 0; s < 2; ++s) {
        const int koff = (((s * 4) + (lane >> 4)) ^ (lane & 7)) * 8;
        f16x8 bfr[4];
#pragma unroll
        for (int ni = 0; ni < 4; ++ni)
          bfr[ni] = *(const f16x8*)(Wc + (wn * 64 + ni * 16 + (lane & 15)) * BK + koff);
        if (p == 0) {
#pragma unroll
          for (int mi = 0; mi < 4; ++mi)
#pragma unroll
            for (int ni = 0; ni < 4; ++ni)
              acc[mi][ni] = __builtin_amdgcn_mfma_f32_16x16x32_f16(xf[mi][s], bfr[ni],
                                                                   acc[mi][ni], 0, 0, 0);
        } else {
          const _Float16 kg = kh[p - 1];
#pragma unroll
          for (int mi = 0; mi < 4; ++mi) {
            const f16x8 af = relu_shift(xf[mi][s], kg);
#pragma unroll
            for (int ni = 0; ni < 4; ++ni)
              acc[mi][ni] = __builtin_amdgcn_mfma_f32_16x16x32_f16(af, bfr[ni],
                                                                   acc[mi][ni], 0, 0, 0);
          }
        }
      }
      __syncthreads();   // drains prefetch (had full compute in flight)
      cur = nxt;
    }
  }

  // epilogue: C/D layout col=lane&15, row=(lane>>4)*4+reg
  const int cn = lane & 15;
  const int r4 = (lane >> 4) * 4;
#pragma unroll
  for (int mi = 0; mi < 4; ++mi) {
    const int rowb = m0 + wm * 64 + mi * 16 + r4;
#pragma unroll
    for (int ni = 0; ni < 4; ++ni) {
      const int col = n0 + wn * 64 + ni * 16 + cn;
#pragma unroll
      for (int reg = 0; reg < 4; ++reg)
        C[(size_t)(rowb + reg) * N + col] = acc[mi][ni][reg];
    }
  }
}

// ---------------- fallback: fp32, wave per (b,o) ----------------
__global__ __launch_bounds__(256) void kan_naive(const float* __restrict__ x,
                                                 const float* __restrict__ bw,
                                                 const float* __restrict__ sw,
                                                 const float* __restrict__ kn,
                                                 float* __restrict__ out) {
  const int lane = threadIdx.x & 63;
  const int o = blockIdx.x * 4 + (threadIdx.x >> 6);
  const int b = blockIdx.y;
  float k[8];
#pragma unroll
  for (int g = 0; g < 8; ++g) k[g] = kn[g];
  float acc = 0.f;
  for (int i = lane; i < IN_F; i += 64) {
    const float v = x[(size_t)b * IN_F + i];
    float sp = 0.f;
    const float* s = sw + ((size_t)o * IN_F + i) * 8;
#pragma unroll
    for (int g = 0; g < 8; ++g) {
      float r = v - k[g];
      sp += s[g] * (r > 0.f ? r : 0.f);
    }
    acc += v * bw[(size_t)o * IN_F + i] + 0.1f * sp;
  }
#pragma unroll
  for (int off = 32; off; off >>= 1) acc += __shfl_down(acc, off, 64);
  if (lane == 0) out[(size_t)b * OUT_F + o] = acc;
}

extern "C" void kernel_launch(void* const* d_in, const int* in_sizes, int n_in,
                              void* d_out, int out_size, void* d_ws, size_t ws_size,
                              hipStream_t stream) {
  const float* x  = (const float*)d_in[0];
  const float* bw = (const float*)d_in[1];
  const float* sw = (const float*)d_in[2];
  const float* kn = (const float*)d_in[3];
  float* out = (float*)d_out;

  const size_t wbytes = (size_t)OUT_F * KDIM * sizeof(_Float16);   // 75.5 MB
  const size_t xbytes = (size_t)BATCH * IN_F * sizeof(_Float16);   // 16.8 MB

  if (ws_size < wbytes + xbytes) {
    dim3 grid(OUT_F / 4, BATCH);
    kan_naive<<<grid, 256, 0, stream>>>(x, bw, sw, kn, out);
    return;
  }

  _Float16* W = (_Float16*)d_ws;
  _Float16* X = (_Float16*)((char*)d_ws + wbytes);

  prep_X<<<(BATCH * IN_F) / 8 / 256, 256, 0, stream>>>(x, X);
  prep_W<<<(OUT_F * IN_F) / 2 / 256, 256, 0, stream>>>(bw, sw, W);
  gemm_kan<<<512, 256, 0, stream>>>(X, W, kn, out);
}